// Round 8
// baseline (203.428 us; speedup 1.0000x reference)
//
#include <hip/hip_runtime.h>
#include <hip/hip_bf16.h>

// ---------- problem constants ----------
#define BB 8
#define TT 2048
#define EE 1024
#define SS 2000
#define HH 150
#define HP 160     // padded hidden (GEMM N)
#define KP2 192    // padded K for layer-2 GEMMs
#define NB 640     // big-GEMM N: [a_w1 | s_w1a | s_w1b | s_w1c] -> 4 x 160
#define NT (BB*TT)     // 16384 tokens
#define NS (BB*SS)     // 16000 spans
#define SPAN_ELEMS ((long)NS*3072)

#define APLANE 520    // 64*8 + 8 ushorts  (16B pad per k-plane: conflict-free writes)
#define BPLANE 1288   // 160*8 + 8 ushorts

typedef __attribute__((ext_vector_type(8))) short short8;
typedef __attribute__((ext_vector_type(4))) float f32x4;
typedef __attribute__((ext_vector_type(4))) ushort u16x4;

__device__ __forceinline__ float b2f(ushort u) {
    union { uint i; float f; } v; v.i = ((uint)u) << 16; return v.f;
}
__device__ __forceinline__ ushort f2b(float f) {
    uint x = __float_as_uint(f);
    uint r = (x + 0x7fffu + ((x >> 16) & 1u)) >> 16;   // RNE
    return (ushort)r;
}
__device__ __forceinline__ float ldf(const void* p, long i, int f32) {
    return f32 ? ((const float*)p)[i] : b2f(((const ushort*)p)[i]);
}

// ---------- dtype detector (1 = inputs are f32, 0 = bf16) ----------
__global__ void detect_kernel(const ushort* __restrict__ p, int* __restrict__ flag) {
    __shared__ int sh;
    if (threadIdx.x == 0) sh = 0;
    __syncthreads();
    int found = 0;
    for (int i = threadIdx.x; i < 65536; i += 1024) {
        ushort v = p[i];
        if ((v & 0x7f80u) >= 0x4780u) found = 1;   // |bf16| >= 65536 (or inf/nan)
    }
    if (found) sh = 1;
    __syncthreads();
    if (threadIdx.x == 0) flag[0] = sh;
}

// ---------- weight prep ----------
__global__ void prep_kernel(const void* __restrict__ a_w1, const void* __restrict__ s_w1,
                            const void* __restrict__ a_w2, const void* __restrict__ s_w2,
                            const void* __restrict__ a_b1, const void* __restrict__ a_b2,
                            const void* __restrict__ s_b1, const void* __restrict__ s_b2,
                            const int* __restrict__ dflag,
                            ushort* __restrict__ Wbig,
                            ushort* __restrict__ a_w2t, ushort* __restrict__ s_w2t,
                            float* __restrict__ biases)
{
    const int f32 = dflag[0];
    int j = blockIdx.x;
    int which = blockIdx.y;
    int t = threadIdx.x;
    if (which == 0) {          // j in 0..639
        int p = j / 160, jj = j - p * 160;
        for (int k = t; k < EE; k += 256) {
            float v = 0.f;
            if (jj < HH)
                v = (p == 0) ? ldf(a_w1, (long)k * HH + jj, f32)
                             : ldf(s_w1, ((long)(p - 1) * EE + k) * HH + jj, f32);
            Wbig[(long)j * EE + k] = f2b(v);
        }
    } else if (which == 1) {
        if (j < HP)
            for (int k = t; k < KP2; k += 256)
                a_w2t[j * KP2 + k] = (j < HH && k < HH) ? f2b(ldf(a_w2, (long)k * HH + j, f32)) : (ushort)0;
    } else if (which == 2) {
        if (j < HP)
            for (int k = t; k < KP2; k += 256)
                s_w2t[j * KP2 + k] = (j < HH && k < HH) ? f2b(ldf(s_w2, (long)k * HH + j, f32)) : (ushort)0;
    } else {
        if (j == 0 && t < HP) {
            biases[t]          = (t < HH) ? ldf(a_b1, t, f32) : 0.f;
            biases[HP + t]     = (t < HH) ? ldf(a_b2, t, f32) : 0.f;
            biases[2*HP + t]   = (t < HH) ? ldf(s_b1, t, f32) : 0.f;
            biases[3*HP + t]   = (t < HH) ? ldf(s_b2, t, f32) : 0.f;
        }
    }
}

// ---------- big token GEMM: embeds[16384][1024] @ Wbig^T -> 4 col-groups ----------
// T14 reg-staged pipeline: issue tile k+1 global loads right after the barrier,
// MFMA tile k on top (loads in flight under compute), regs->LDS next iteration.
// LDS k-planes padded +16B so A/B ds_write_b128 are bank-conflict-free.
__global__ __launch_bounds__(256) void big_gemm_kernel(
    const void* __restrict__ A, const int* __restrict__ dflag,
    const ushort* __restrict__ Wbig,
    const float* __restrict__ biases,
    ushort* __restrict__ h1a, ushort* __restrict__ Pabc)
{
    __shared__ __align__(16) ushort A2[8*APLANE];   // 8.3 KB
    __shared__ __align__(16) ushort B2[8*BPLANE];   // 20.6 KB

    const int af32 = dflag[0];
    const int t = threadIdx.x;
    const int row0 = blockIdx.x * 64;
    const int cg = blockIdx.y;
    const int lane = t & 63;
    const int w = t >> 6;
    const int wr = w >> 1;
    const int wc = w & 1;
    const int l15 = lane & 15;
    const int lg = lane >> 4;       // 0..3

    f32x4 acc[2][5];
#pragma unroll
    for (int m = 0; m < 2; ++m)
#pragma unroll
        for (int n = 0; n < 5; ++n) acc[m][n] = (f32x4){0.f, 0.f, 0.f, 0.f};

    const int arow = t >> 2;            // 0..63
    const int acol = (t & 3) * 16;      // element offset within K-tile
    ushort* aw0 = &A2[((t & 3) * 2    ) * APLANE + arow * 8];
    ushort* aw1 = &A2[((t & 3) * 2 + 1) * APLANE + arow * 8];

    const float*  srcF = (const float*)A  + (long)(row0 + arow) * EE + acol;
    const ushort* srcH = (const ushort*)A + (long)(row0 + arow) * EE + acol;

    // staging registers
    f32x4 raf[4];
    uint4 rab[2];
    uint4 rb[5];

    auto load_tile = [&](int k0) {
        if (af32) {
#pragma unroll
            for (int q = 0; q < 4; ++q) raf[q] = *(const f32x4*)(srcF + k0 + q * 4);
        } else {
            rab[0] = *(const uint4*)(srcH + k0);
            rab[1] = *(const uint4*)(srcH + k0 + 8);
        }
#pragma unroll
        for (int p = 0; p < 5; ++p) {
            int g = p * 256 + t;
            rb[p] = *(const uint4*)(Wbig + (long)(cg * 160 + (g >> 3)) * EE + k0 + (g & 7) * 8);
        }
    };
    auto write_tile = [&]() {
        if (af32) {
            ushort tmp[16];
#pragma unroll
            for (int q = 0; q < 4; ++q) {
                tmp[4*q+0] = f2b(raf[q][0]); tmp[4*q+1] = f2b(raf[q][1]);
                tmp[4*q+2] = f2b(raf[q][2]); tmp[4*q+3] = f2b(raf[q][3]);
            }
            *(uint4*)aw0 = *(uint4*)&tmp[0];
            *(uint4*)aw1 = *(uint4*)&tmp[8];
        } else {
            *(uint4*)aw0 = rab[0];
            *(uint4*)aw1 = rab[1];
        }
#pragma unroll
        for (int p = 0; p < 5; ++p) {
            int g = p * 256 + t;
            *(uint4*)&B2[(g & 7) * BPLANE + (g >> 3) * 8] = rb[p];
        }
    };

    load_tile(0);
    for (int k0 = 0; k0 < EE; k0 += 64) {
        if (k0) __syncthreads();        // prev tile's MFMA reads done before overwrite
        write_tile();                   // regs (waitcnt'd) -> LDS
        __syncthreads();                // LDS visible
        if (k0 + 64 < EE) load_tile(k0 + 64);   // issue next loads; land during MFMA
#pragma unroll
        for (int ks = 0; ks < 2; ++ks) {
            const int kg = ks * 4 + lg;
            short8 af2[2];
#pragma unroll
            for (int m = 0; m < 2; ++m)
                af2[m] = *(const short8*)&A2[kg * APLANE + (wr*32 + m*16 + l15) * 8];
#pragma unroll
            for (int n = 0; n < 5; ++n) {
                short8 bf = *(const short8*)&B2[kg * BPLANE + (wc*80 + n*16 + l15) * 8];
#pragma unroll
                for (int m = 0; m < 2; ++m)
                    acc[m][n] = __builtin_amdgcn_mfma_f32_16x16x32_bf16(af2[m], bf, acc[m][n], 0, 0, 0);
            }
        }
    }
    if (cg == 0) {
#pragma unroll
        for (int m = 0; m < 2; ++m) {
            int rbase = row0 + wr*32 + m*16 + lg * 4;
#pragma unroll
            for (int n = 0; n < 5; ++n) {
                int col = wc*80 + n*16 + l15;
                float b = biases[col];
#pragma unroll
                for (int r = 0; r < 4; ++r) {
                    float v = acc[m][n][r] + b;
                    v = v > 0.f ? v : 0.f;
                    h1a[(long)(rbase + r) * KP2 + col] = f2b(v);
                }
            }
        }
        int r = t >> 2;
        int c = HP + (t & 3) * 8;
        *(uint4*)(h1a + (long)(row0 + r) * KP2 + c) = (uint4){0,0,0,0};
    } else {
        int cb = (cg - 1) * 160;
#pragma unroll
        for (int m = 0; m < 2; ++m) {
            int rbase = row0 + wr*32 + m*16 + lg * 4;
#pragma unroll
            for (int n = 0; n < 5; ++n) {
                int col = cb + wc*80 + n*16 + l15;
#pragma unroll
                for (int r = 0; r < 4; ++r)
                    Pabc[(long)(rbase + r) * 480 + col] = f2b(acc[m][n][r]);
            }
        }
    }
}

// ---------- fused layer-2 GEMM + score dot ----------
// score[row] = b3 + sum_col relu(A[row]@Wt[col] + bias[col]) * w3[col]
__global__ __launch_bounds__(256) void gemm_relu_dot_kernel(
    const ushort* __restrict__ A,
    const ushort* __restrict__ Wt,
    const float* __restrict__ bias,
    const void* __restrict__ w3, const void* __restrict__ b3,
    const int* __restrict__ dflag,
    float* __restrict__ outf, void* __restrict__ outAll)
{
    __shared__ __align__(16) ushort A2[8*64*8];
    __shared__ __align__(16) ushort B2[8*160*8];
    __shared__ float w3lds[HP];
    __shared__ float red[64][2];

    const int f32 = dflag[0];
    const int t = threadIdx.x;
    const int row0 = blockIdx.x * 64;
    const int lane = t & 63;
    const int w = t >> 6;
    const int wr = w >> 1;
    const int wc = w & 1;
    const int l15 = lane & 15;
    const int kb = (lane >> 4) * 8;

    if (t < HP) w3lds[t] = (t < HH) ? ldf(w3, t, f32) : 0.f;

    f32x4 acc[2][5];
#pragma unroll
    for (int m = 0; m < 2; ++m)
#pragma unroll
        for (int n = 0; n < 5; ++n) acc[m][n] = (f32x4){0.f, 0.f, 0.f, 0.f};

    const int arow = t >> 2;
    const int ag0 = (t & 3) * 2;

    for (int k0 = 0; k0 < KP2; k0 += 64) {
        {
            const ushort* src = A + (long)(row0 + arow) * KP2 + k0 + ag0 * 8;
            *(uint4*)&A2[((ag0    ) * 64 + arow) * 8] = *(const uint4*)(src);
            *(uint4*)&A2[((ag0 + 1) * 64 + arow) * 8] = *(const uint4*)(src + 8);
        }
#pragma unroll
        for (int p = 0; p < 5; ++p) {
            int gg = p * 256 + t;
            int br = gg >> 3;
            int bg = gg & 7;
            uint4 v = *(const uint4*)(Wt + (long)br * KP2 + k0 + bg * 8);
            *(uint4*)&B2[(bg * 160 + br) * 8] = v;
        }
        __syncthreads();
#pragma unroll
        for (int ks = 0; ks < 64; ks += 32) {
            const int kg = (ks + kb) >> 3;
            short8 af[2];
#pragma unroll
            for (int m = 0; m < 2; ++m)
                af[m] = *(const short8*)&A2[(kg * 64 + wr*32 + m*16 + l15) * 8];
#pragma unroll
            for (int n = 0; n < 5; ++n) {
                short8 bf = *(const short8*)&B2[(kg * 160 + wc*80 + n*16 + l15) * 8];
#pragma unroll
                for (int m = 0; m < 2; ++m)
                    acc[m][n] = __builtin_amdgcn_mfma_f32_16x16x32_bf16(af[m], bf, acc[m][n], 0, 0, 0);
            }
        }
        __syncthreads();
    }
    // epilogue: relu + dot(w3) fused, no h2 materialization
    float w3c[5];
    float bc[5];
#pragma unroll
    for (int n = 0; n < 5; ++n) {
        int col = wc*80 + n*16 + l15;
        w3c[n] = w3lds[col];
        bc[n] = bias[col];
    }
    float p[2][4];
#pragma unroll
    for (int m = 0; m < 2; ++m)
#pragma unroll
        for (int r = 0; r < 4; ++r) {
            float s = 0.f;
#pragma unroll
            for (int n = 0; n < 5; ++n) {
                float v = acc[m][n][r] + bc[n];
                v = v > 0.f ? v : 0.f;
                s += v * w3c[n];
            }
            p[m][r] = s;
        }
#pragma unroll
    for (int mask = 1; mask < 16; mask <<= 1)
#pragma unroll
        for (int m = 0; m < 2; ++m)
#pragma unroll
            for (int r = 0; r < 4; ++r)
                p[m][r] += __shfl_xor(p[m][r], mask, 16);
    if (l15 == 0) {
        int g = lane >> 4;
#pragma unroll
        for (int m = 0; m < 2; ++m)
#pragma unroll
            for (int r = 0; r < 4; ++r)
                red[wr*32 + m*16 + g*4 + r][wc] = p[m][r];
    }
    __syncthreads();
    if (t < 64) {
        int row = row0 + t;
        float s = red[t][0] + red[t][1] + ldf(b3, 0, f32);
        if (outf) outf[row] = s;
        else if (f32) ((float*)outAll)[SPAN_ELEMS + row] = s;
        else ((ushort*)outAll)[SPAN_ELEMS + row] = f2b(s);
    }
}

// ---------- span: out0 = [start_e|end_e|span_sum]; h1m = relu(Pa+Pb+Σa·Pc+b) ----------
// 1D grid 16000 with bijective XCD swizzle: XCD k owns batch k's spans in sorted order.
__global__ __launch_bounds__(256) void span_kernel(
    const void* __restrict__ embeds, const float* __restrict__ attns,
    const int* __restrict__ starts, const int* __restrict__ lens,
    void* __restrict__ out, const int* __restrict__ dflag,
    const ushort* __restrict__ Pabc, const float* __restrict__ biases2,
    ushort* __restrict__ h1m)
{
    __shared__ float at[32];
    const int f32 = dflag[0];
    int bid = blockIdx.x;
    int swz = (bid & 7) * (NS / 8) + (bid >> 3);   // bijective (16000 % 8 == 0)
    int b = swz / SS, s = swz - b * SS;
    int t = threadIdx.x;
    int st = starts[b*SS + s];
    int len = lens[b*SS + s];       // inclusive span st..st+len, len+1 <= 30 rows
    int en = st + len;
    if (t < 30) at[t] = attns[b*TT + st + t];
    __syncthreads();
    // ---- phase A: span_embeds -> out (non-temporal stores keep L2 for gather) ----
    int e4 = t * 4;
    long ebase = ((long)(b*TT + st)) * EE + e4;
    long eend  = ((long)(b*TT + en)) * EE + e4;
    long obase = ((long)(b*SS + s)) * 3072 + e4;
    if (!f32) {
        const ushort* E = (const ushort*)embeds;
        ushort* O = (ushort*)out;
        u16x4 se = *(const u16x4*)(E + ebase);
        u16x4 ed = *(const u16x4*)(E + eend);
        float ax = 0.f, ay = 0.f, az = 0.f, aw = 0.f;
        for (int i = 0; i <= len; ++i) {
            float a = at[i];
            u16x4 v = *(const u16x4*)(E + ebase + (long)i * EE);
            ax += b2f(v.x) * a; ay += b2f(v.y) * a;
            az += b2f(v.z) * a; aw += b2f(v.w) * a;
        }
        u16x4 sm; sm.x = f2b(ax); sm.y = f2b(ay); sm.z = f2b(az); sm.w = f2b(aw);
        __builtin_nontemporal_store(se, (u16x4*)(O + obase));
        __builtin_nontemporal_store(ed, (u16x4*)(O + obase + 1024));
        __builtin_nontemporal_store(sm, (u16x4*)(O + obase + 2048));
    } else {
        const float* E = (const float*)embeds;
        float* O = (float*)out;
        f32x4 se = *(const f32x4*)(E + ebase);
        f32x4 ed = *(const f32x4*)(E + eend);
        float ax = 0.f, ay = 0.f, az = 0.f, aw = 0.f;
        for (int i = 0; i <= len; ++i) {
            float a = at[i];
            f32x4 v = *(const f32x4*)(E + ebase + (long)i * EE);
            ax += v.x * a; ay += v.y * a; az += v.z * a; aw += v.w * a;
        }
        f32x4 sm = {ax, ay, az, aw};
        __builtin_nontemporal_store(se, (f32x4*)(O + obase));
        __builtin_nontemporal_store(ed, (f32x4*)(O + obase + 1024));
        __builtin_nontemporal_store(sm, (f32x4*)(O + obase + 2048));
    }
    // ---- phase B: mention-layer-1 row via linearity ----
    long rowi = (long)(b*SS + s);
    if (t < HP) {
        float acc = biases2[t]
                  + b2f(Pabc[((long)(b*TT + st)) * 480 + t])
                  + b2f(Pabc[((long)(b*TT + en)) * 480 + 160 + t]);
        const ushort* pc = Pabc + ((long)(b*TT + st)) * 480 + 320 + t;
        for (int i = 0; i <= len; ++i) acc += at[i] * b2f(pc[(long)i * 480]);
        acc = acc > 0.f ? acc : 0.f;
        h1m[rowi * KP2 + t] = f2b(acc);
    } else if (t < KP2) {
        h1m[rowi * KP2 + t] = 0;
    }
}

extern "C" void kernel_launch(void* const* d_in, const int* in_sizes, int n_in,
                              void* d_out, int out_size, void* d_ws, size_t ws_size,
                              hipStream_t stream)
{
    const void* embeds = d_in[0];
    const void* a_w1 = d_in[1];  const void* a_b1 = d_in[2];
    const void* a_w2 = d_in[3];  const void* a_b2 = d_in[4];
    const void* a_w3 = d_in[5];  const void* a_b3 = d_in[6];
    const void* s_w1 = d_in[7];  const void* s_b1 = d_in[8];
    const void* s_w2 = d_in[9];  const void* s_b2 = d_in[10];
    const void* s_w3 = d_in[11]; const void* s_b3 = d_in[12];
    const int* starts = (const int*)d_in[13];
    const int* lens   = (const int*)d_in[14];

    // workspace layout — ~30 MB
    char* ws = (char*)d_ws;
    int*    dflag = (int*)ws;                  ws += 256;
    ushort* Wbig  = (ushort*)ws;               ws += (size_t)NB*EE*2;        // 1.31 MB
    ushort* a_w2t = (ushort*)ws;               ws += (size_t)HP*KP2*2;       // 60 KB
    ushort* s_w2t = (ushort*)ws;               ws += (size_t)HP*KP2*2;       // 60 KB
    float*  biases = (float*)ws;               ws += (size_t)4*HP*4;         // 2.5 KB
    ushort* h1a  = (ushort*)ws;                ws += (size_t)NT*KP2*2;       // 6.3 MB
    ushort* Pabc = (ushort*)ws;                ws += (size_t)NT*480*2;       // 15.7 MB
    float*  attns = (float*)ws;                ws += (size_t)NT*4;           // 64 KB
    ushort* h1m  = (ushort*)ws;                ws += (size_t)NS*KP2*2;       // 6.1 MB

    detect_kernel<<<1, 1024, 0, stream>>>((const ushort*)embeds, dflag);
    prep_kernel<<<dim3(NB, 4), 256, 0, stream>>>(a_w1, s_w1, a_w2, s_w2,
                                                 a_b1, a_b2, s_b1, s_b2, dflag,
                                                 Wbig, a_w2t, s_w2t, biases);
    // token-level fused layer-1 GEMM (attn h1 + mention projections Pa,Pb,Pc)
    big_gemm_kernel<<<dim3(NT/64, 4), 256, 0, stream>>>(embeds, dflag, Wbig, biases, h1a, Pabc);
    // attn layer-2 + score (fused)
    gemm_relu_dot_kernel<<<NT/64, 256, 0, stream>>>(h1a, a_w2t, biases + HP,
                                                    a_w3, a_b3, dflag, attns, nullptr);
    // spans: output 0 + mention h1 via linearity (XCD-swizzled)
    span_kernel<<<NS, 256, 0, stream>>>(embeds, attns, starts, lens, d_out, dflag,
                                        Pabc, biases + 2*HP, h1m);
    // mention layer-2 + score (fused)
    gemm_relu_dot_kernel<<<NS/64, 256, 0, stream>>>(h1m, s_w2t, biases + 3*HP,
                                                    s_w3, s_b3, dflag, nullptr, d_out);
}

// Round 9
// 132.203 us; speedup vs baseline: 1.5387x; 1.5387x over previous
//
#include <hip/hip_runtime.h>
#include <hip/hip_bf16.h>

// ---------- problem constants ----------
#define BB 8
#define TT 2048
#define EE 1024
#define SS 2000
#define HH 150
#define HP 160     // padded hidden (GEMM N)
#define KP2 192    // padded K for layer-2 GEMMs
#define NB 640     // big-GEMM N: [a_w1 | s_w1a | s_w1b | s_w1c] -> 4 x 160
#define NT (BB*TT)     // 16384 tokens
#define NS (BB*SS)     // 16000 spans
#define SPAN_ELEMS ((long)NS*3072)

#define APLANE 520    // 64*8 + 8 ushorts  (16B pad per k-plane: conflict-free writes)
#define BPLANE 1288   // 160*8 + 8 ushorts

typedef __attribute__((ext_vector_type(8))) short short8;
typedef __attribute__((ext_vector_type(4))) float f32x4;
typedef __attribute__((ext_vector_type(4))) ushort u16x4;

__device__ __forceinline__ float b2f(ushort u) {
    union { uint i; float f; } v; v.i = ((uint)u) << 16; return v.f;
}
__device__ __forceinline__ ushort f2b(float f) {
    uint x = __float_as_uint(f);
    uint r = (x + 0x7fffu + ((x >> 16) & 1u)) >> 16;   // RNE
    return (ushort)r;
}
__device__ __forceinline__ uint f2b2(float lo, float hi) {   // pack 2 bf16 into u32
    return (uint)f2b(lo) | ((uint)f2b(hi) << 16);
}
__device__ __forceinline__ float ldf(const void* p, long i, int f32) {
    return f32 ? ((const float*)p)[i] : b2f(((const ushort*)p)[i]);
}

// ---------- dtype detector (1 = inputs are f32, 0 = bf16) ----------
__global__ void detect_kernel(const ushort* __restrict__ p, int* __restrict__ flag) {
    __shared__ int sh;
    if (threadIdx.x == 0) sh = 0;
    __syncthreads();
    int found = 0;
    for (int i = threadIdx.x; i < 65536; i += 1024) {
        ushort v = p[i];
        if ((v & 0x7f80u) >= 0x4780u) found = 1;   // |bf16| >= 65536 (or inf/nan)
    }
    if (found) sh = 1;
    __syncthreads();
    if (threadIdx.x == 0) flag[0] = sh;
}

// ---------- weight prep ----------
__global__ void prep_kernel(const void* __restrict__ a_w1, const void* __restrict__ s_w1,
                            const void* __restrict__ a_w2, const void* __restrict__ s_w2,
                            const void* __restrict__ a_b1, const void* __restrict__ a_b2,
                            const void* __restrict__ s_b1, const void* __restrict__ s_b2,
                            const int* __restrict__ dflag,
                            ushort* __restrict__ Wbig,
                            ushort* __restrict__ a_w2t, ushort* __restrict__ s_w2t,
                            float* __restrict__ biases)
{
    const int f32 = dflag[0];
    int j = blockIdx.x;
    int which = blockIdx.y;
    int t = threadIdx.x;
    if (which == 0) {          // j in 0..639
        int p = j / 160, jj = j - p * 160;
        for (int k = t; k < EE; k += 256) {
            float v = 0.f;
            if (jj < HH)
                v = (p == 0) ? ldf(a_w1, (long)k * HH + jj, f32)
                             : ldf(s_w1, ((long)(p - 1) * EE + k) * HH + jj, f32);
            Wbig[(long)j * EE + k] = f2b(v);
        }
    } else if (which == 1) {
        if (j < HP)
            for (int k = t; k < KP2; k += 256)
                a_w2t[j * KP2 + k] = (j < HH && k < HH) ? f2b(ldf(a_w2, (long)k * HH + j, f32)) : (ushort)0;
    } else if (which == 2) {
        if (j < HP)
            for (int k = t; k < KP2; k += 256)
                s_w2t[j * KP2 + k] = (j < HH && k < HH) ? f2b(ldf(s_w2, (long)k * HH + j, f32)) : (ushort)0;
    } else {
        if (j == 0 && t < HP) {
            biases[t]          = (t < HH) ? ldf(a_b1, t, f32) : 0.f;
            biases[HP + t]     = (t < HH) ? ldf(a_b2, t, f32) : 0.f;
            biases[2*HP + t]   = (t < HH) ? ldf(s_b1, t, f32) : 0.f;
            biases[3*HP + t]   = (t < HH) ? ldf(s_b2, t, f32) : 0.f;
        }
    }
}

// ---------- big token GEMM: embeds[16384][1024] @ Wbig^T -> 4 col-groups ----------
// T14 reg-staged pipeline with EXPLICIT named staging registers (no arrays/lambdas
// -> nothing can demote to scratch). Loads for tile k+1 issue right after the
// barrier and land while tile k's MFMAs run. LDS planes padded (conflict-free).
__global__ __launch_bounds__(256, 2) void big_gemm_kernel(
    const void* __restrict__ A, const int* __restrict__ dflag,
    const ushort* __restrict__ Wbig,
    const float* __restrict__ biases,
    ushort* __restrict__ h1a, ushort* __restrict__ Pabc)
{
    __shared__ __align__(16) ushort A2[8*APLANE];   // 8.3 KB
    __shared__ __align__(16) ushort B2[8*BPLANE];   // 20.6 KB

    const int af32 = dflag[0];
    const int t = threadIdx.x;
    const int row0 = blockIdx.x * 64;
    const int cg = blockIdx.y;
    const int lane = t & 63;
    const int w = t >> 6;
    const int wr = w >> 1;
    const int wc = w & 1;
    const int l15 = lane & 15;
    const int lg = lane >> 4;       // 0..3

    f32x4 acc[2][5];
#pragma unroll
    for (int m = 0; m < 2; ++m)
#pragma unroll
        for (int n = 0; n < 5; ++n) acc[m][n] = (f32x4){0.f, 0.f, 0.f, 0.f};

    const int arow = t >> 2;            // 0..63
    const int acol = (t & 3) * 16;      // element offset within K-tile

    // LDS write pointers (loop-invariant)
    ushort* aw0 = &A2[((t & 3) * 2    ) * APLANE + arow * 8];
    ushort* aw1 = &A2[((t & 3) * 2 + 1) * APLANE + arow * 8];
    ushort* bw0 = &B2[(t & 7) * BPLANE + (0*32 + (t >> 3)) * 8];
    ushort* bw1 = &B2[(t & 7) * BPLANE + (1*32 + (t >> 3)) * 8];
    ushort* bw2 = &B2[(t & 7) * BPLANE + (2*32 + (t >> 3)) * 8];
    ushort* bw3 = &B2[(t & 7) * BPLANE + (3*32 + (t >> 3)) * 8];
    ushort* bw4 = &B2[(t & 7) * BPLANE + (4*32 + (t >> 3)) * 8];

    // global source pointers (advance by k0)
    const float*  srcF = (const float*)A  + (long)(row0 + arow) * EE + acol;
    const ushort* srcH = (const ushort*)A + (long)(row0 + arow) * EE + acol;
    const ushort* bs0 = Wbig + (long)(cg*160 + 0*32 + (t >> 3)) * EE + (t & 7) * 8;
    const ushort* bs1 = Wbig + (long)(cg*160 + 1*32 + (t >> 3)) * EE + (t & 7) * 8;
    const ushort* bs2 = Wbig + (long)(cg*160 + 2*32 + (t >> 3)) * EE + (t & 7) * 8;
    const ushort* bs3 = Wbig + (long)(cg*160 + 3*32 + (t >> 3)) * EE + (t & 7) * 8;
    const ushort* bs4 = Wbig + (long)(cg*160 + 4*32 + (t >> 3)) * EE + (t & 7) * 8;

    // named staging registers
    f32x4 raf0, raf1, raf2, raf3;
    uint4 rab0, rab1;
    uint4 rb0, rb1, rb2, rb3, rb4;

#define LOAD_TILE(K0)                                                          \
    do {                                                                       \
        if (af32) {                                                            \
            raf0 = *(const f32x4*)(srcF + (K0));                               \
            raf1 = *(const f32x4*)(srcF + (K0) + 4);                           \
            raf2 = *(const f32x4*)(srcF + (K0) + 8);                           \
            raf3 = *(const f32x4*)(srcF + (K0) + 12);                          \
        } else {                                                               \
            rab0 = *(const uint4*)(srcH + (K0));                               \
            rab1 = *(const uint4*)(srcH + (K0) + 8);                           \
        }                                                                      \
        rb0 = *(const uint4*)(bs0 + (K0));                                     \
        rb1 = *(const uint4*)(bs1 + (K0));                                     \
        rb2 = *(const uint4*)(bs2 + (K0));                                     \
        rb3 = *(const uint4*)(bs3 + (K0));                                     \
        rb4 = *(const uint4*)(bs4 + (K0));                                     \
    } while (0)

#define WRITE_TILE()                                                           \
    do {                                                                       \
        if (af32) {                                                            \
            uint4 w0, w1;                                                      \
            w0.x = f2b2(raf0[0], raf0[1]); w0.y = f2b2(raf0[2], raf0[3]);      \
            w0.z = f2b2(raf1[0], raf1[1]); w0.w = f2b2(raf1[2], raf1[3]);      \
            w1.x = f2b2(raf2[0], raf2[1]); w1.y = f2b2(raf2[2], raf2[3]);      \
            w1.z = f2b2(raf3[0], raf3[1]); w1.w = f2b2(raf3[2], raf3[3]);      \
            *(uint4*)aw0 = w0;                                                 \
            *(uint4*)aw1 = w1;                                                 \
        } else {                                                               \
            *(uint4*)aw0 = rab0;                                               \
            *(uint4*)aw1 = rab1;                                               \
        }                                                                      \
        *(uint4*)bw0 = rb0;                                                    \
        *(uint4*)bw1 = rb1;                                                    \
        *(uint4*)bw2 = rb2;                                                    \
        *(uint4*)bw3 = rb3;                                                    \
        *(uint4*)bw4 = rb4;                                                    \
    } while (0)

    LOAD_TILE(0);
    for (int k0 = 0; k0 < EE; k0 += 64) {
        if (k0) __syncthreads();        // prev tile's MFMA reads done before overwrite
        WRITE_TILE();                   // regs (waitcnt'd) -> LDS
        __syncthreads();                // LDS visible
        if (k0 + 64 < EE) LOAD_TILE(k0 + 64);   // in flight under MFMA phase
#pragma unroll
        for (int ks = 0; ks < 2; ++ks) {
            const int kg = ks * 4 + lg;
            short8 af2[2];
#pragma unroll
            for (int m = 0; m < 2; ++m)
                af2[m] = *(const short8*)&A2[kg * APLANE + (wr*32 + m*16 + l15) * 8];
#pragma unroll
            for (int n = 0; n < 5; ++n) {
                short8 bf = *(const short8*)&B2[kg * BPLANE + (wc*80 + n*16 + l15) * 8];
#pragma unroll
                for (int m = 0; m < 2; ++m)
                    acc[m][n] = __builtin_amdgcn_mfma_f32_16x16x32_bf16(af2[m], bf, acc[m][n], 0, 0, 0);
            }
        }
    }
#undef LOAD_TILE
#undef WRITE_TILE
    if (cg == 0) {
#pragma unroll
        for (int m = 0; m < 2; ++m) {
            int rbase = row0 + wr*32 + m*16 + lg * 4;
#pragma unroll
            for (int n = 0; n < 5; ++n) {
                int col = wc*80 + n*16 + l15;
                float b = biases[col];
#pragma unroll
                for (int r = 0; r < 4; ++r) {
                    float v = acc[m][n][r] + b;
                    v = v > 0.f ? v : 0.f;
                    h1a[(long)(rbase + r) * KP2 + col] = f2b(v);
                }
            }
        }
        int r = t >> 2;
        int c = HP + (t & 3) * 8;
        *(uint4*)(h1a + (long)(row0 + r) * KP2 + c) = (uint4){0,0,0,0};
    } else {
        int cb = (cg - 1) * 160;
#pragma unroll
        for (int m = 0; m < 2; ++m) {
            int rbase = row0 + wr*32 + m*16 + lg * 4;
#pragma unroll
            for (int n = 0; n < 5; ++n) {
                int col = cb + wc*80 + n*16 + l15;
#pragma unroll
                for (int r = 0; r < 4; ++r)
                    Pabc[(long)(rbase + r) * 480 + col] = f2b(acc[m][n][r]);
            }
        }
    }
}

// ---------- fused layer-2 GEMM + score dot ----------
// score[row] = b3 + sum_col relu(A[row]@Wt[col] + bias[col]) * w3[col]
__global__ __launch_bounds__(256) void gemm_relu_dot_kernel(
    const ushort* __restrict__ A,
    const ushort* __restrict__ Wt,
    const float* __restrict__ bias,
    const void* __restrict__ w3, const void* __restrict__ b3,
    const int* __restrict__ dflag,
    float* __restrict__ outf, void* __restrict__ outAll)
{
    __shared__ __align__(16) ushort A2[8*64*8];
    __shared__ __align__(16) ushort B2[8*160*8];
    __shared__ float w3lds[HP];
    __shared__ float red[64][2];

    const int f32 = dflag[0];
    const int t = threadIdx.x;
    const int row0 = blockIdx.x * 64;
    const int lane = t & 63;
    const int w = t >> 6;
    const int wr = w >> 1;
    const int wc = w & 1;
    const int l15 = lane & 15;
    const int kb = (lane >> 4) * 8;

    if (t < HP) w3lds[t] = (t < HH) ? ldf(w3, t, f32) : 0.f;

    f32x4 acc[2][5];
#pragma unroll
    for (int m = 0; m < 2; ++m)
#pragma unroll
        for (int n = 0; n < 5; ++n) acc[m][n] = (f32x4){0.f, 0.f, 0.f, 0.f};

    const int arow = t >> 2;
    const int ag0 = (t & 3) * 2;

    for (int k0 = 0; k0 < KP2; k0 += 64) {
        {
            const ushort* src = A + (long)(row0 + arow) * KP2 + k0 + ag0 * 8;
            *(uint4*)&A2[((ag0    ) * 64 + arow) * 8] = *(const uint4*)(src);
            *(uint4*)&A2[((ag0 + 1) * 64 + arow) * 8] = *(const uint4*)(src + 8);
        }
#pragma unroll
        for (int p = 0; p < 5; ++p) {
            int gg = p * 256 + t;
            int br = gg >> 3;
            int bg = gg & 7;
            uint4 v = *(const uint4*)(Wt + (long)br * KP2 + k0 + bg * 8);
            *(uint4*)&B2[(bg * 160 + br) * 8] = v;
        }
        __syncthreads();
#pragma unroll
        for (int ks = 0; ks < 64; ks += 32) {
            const int kg = (ks + kb) >> 3;
            short8 af[2];
#pragma unroll
            for (int m = 0; m < 2; ++m)
                af[m] = *(const short8*)&A2[(kg * 64 + wr*32 + m*16 + l15) * 8];
#pragma unroll
            for (int n = 0; n < 5; ++n) {
                short8 bf = *(const short8*)&B2[(kg * 160 + wc*80 + n*16 + l15) * 8];
#pragma unroll
                for (int m = 0; m < 2; ++m)
                    acc[m][n] = __builtin_amdgcn_mfma_f32_16x16x32_bf16(af[m], bf, acc[m][n], 0, 0, 0);
            }
        }
        __syncthreads();
    }
    // epilogue: relu + dot(w3) fused, no h2 materialization
    float w3c[5];
    float bc[5];
#pragma unroll
    for (int n = 0; n < 5; ++n) {
        int col = wc*80 + n*16 + l15;
        w3c[n] = w3lds[col];
        bc[n] = bias[col];
    }
    float p[2][4];
#pragma unroll
    for (int m = 0; m < 2; ++m)
#pragma unroll
        for (int r = 0; r < 4; ++r) {
            float s = 0.f;
#pragma unroll
            for (int n = 0; n < 5; ++n) {
                float v = acc[m][n][r] + bc[n];
                v = v > 0.f ? v : 0.f;
                s += v * w3c[n];
            }
            p[m][r] = s;
        }
#pragma unroll
    for (int mask = 1; mask < 16; mask <<= 1)
#pragma unroll
        for (int m = 0; m < 2; ++m)
#pragma unroll
            for (int r = 0; r < 4; ++r)
                p[m][r] += __shfl_xor(p[m][r], mask, 16);
    if (l15 == 0) {
        int g = lane >> 4;
#pragma unroll
        for (int m = 0; m < 2; ++m)
#pragma unroll
            for (int r = 0; r < 4; ++r)
                red[wr*32 + m*16 + g*4 + r][wc] = p[m][r];
    }
    __syncthreads();
    if (t < 64) {
        int row = row0 + t;
        float s = red[t][0] + red[t][1] + ldf(b3, 0, f32);
        if (outf) outf[row] = s;
        else if (f32) ((float*)outAll)[SPAN_ELEMS + row] = s;
        else ((ushort*)outAll)[SPAN_ELEMS + row] = f2b(s);
    }
}

// ---------- span: out0 = [start_e|end_e|span_sum]; h1m = relu(Pa+Pb+Σa·Pc+b) ----------
// 1D grid 16000 with bijective XCD swizzle: XCD k owns batch k's spans in sorted order.
__global__ __launch_bounds__(256) void span_kernel(
    const void* __restrict__ embeds, const float* __restrict__ attns,
    const int* __restrict__ starts, const int* __restrict__ lens,
    void* __restrict__ out, const int* __restrict__ dflag,
    const ushort* __restrict__ Pabc, const float* __restrict__ biases2,
    ushort* __restrict__ h1m)
{
    __shared__ float at[32];
    const int f32 = dflag[0];
    int bid = blockIdx.x;
    int swz = (bid & 7) * (NS / 8) + (bid >> 3);   // bijective (16000 % 8 == 0)
    int b = swz / SS, s = swz - b * SS;
    int t = threadIdx.x;
    int st = starts[b*SS + s];
    int len = lens[b*SS + s];       // inclusive span st..st+len, len+1 <= 30 rows
    int en = st + len;
    if (t < 30) at[t] = attns[b*TT + st + t];
    __syncthreads();
    // ---- phase A: span_embeds -> out (non-temporal stores keep L2 for gather) ----
    int e4 = t * 4;
    long ebase = ((long)(b*TT + st)) * EE + e4;
    long eend  = ((long)(b*TT + en)) * EE + e4;
    long obase = ((long)(b*SS + s)) * 3072 + e4;
    if (!f32) {
        const ushort* E = (const ushort*)embeds;
        ushort* O = (ushort*)out;
        u16x4 se = *(const u16x4*)(E + ebase);
        u16x4 ed = *(const u16x4*)(E + eend);
        float ax = 0.f, ay = 0.f, az = 0.f, aw = 0.f;
        for (int i = 0; i <= len; ++i) {
            float a = at[i];
            u16x4 v = *(const u16x4*)(E + ebase + (long)i * EE);
            ax += b2f(v.x) * a; ay += b2f(v.y) * a;
            az += b2f(v.z) * a; aw += b2f(v.w) * a;
        }
        u16x4 sm; sm.x = f2b(ax); sm.y = f2b(ay); sm.z = f2b(az); sm.w = f2b(aw);
        __builtin_nontemporal_store(se, (u16x4*)(O + obase));
        __builtin_nontemporal_store(ed, (u16x4*)(O + obase + 1024));
        __builtin_nontemporal_store(sm, (u16x4*)(O + obase + 2048));
    } else {
        const float* E = (const float*)embeds;
        float* O = (float*)out;
        f32x4 se = *(const f32x4*)(E + ebase);
        f32x4 ed = *(const f32x4*)(E + eend);
        float ax = 0.f, ay = 0.f, az = 0.f, aw = 0.f;
        for (int i = 0; i <= len; ++i) {
            float a = at[i];
            f32x4 v = *(const f32x4*)(E + ebase + (long)i * EE);
            ax += v.x * a; ay += v.y * a; az += v.z * a; aw += v.w * a;
        }
        f32x4 sm = {ax, ay, az, aw};
        __builtin_nontemporal_store(se, (f32x4*)(O + obase));
        __builtin_nontemporal_store(ed, (f32x4*)(O + obase + 1024));
        __builtin_nontemporal_store(sm, (f32x4*)(O + obase + 2048));
    }
    // ---- phase B: mention-layer-1 row via linearity ----
    long rowi = (long)(b*SS + s);
    if (t < HP) {
        float acc = biases2[t]
                  + b2f(Pabc[((long)(b*TT + st)) * 480 + t])
                  + b2f(Pabc[((long)(b*TT + en)) * 480 + 160 + t]);
        const ushort* pc = Pabc + ((long)(b*TT + st)) * 480 + 320 + t;
        for (int i = 0; i <= len; ++i) acc += at[i] * b2f(pc[(long)i * 480]);
        acc = acc > 0.f ? acc : 0.f;
        h1m[rowi * KP2 + t] = f2b(acc);
    } else if (t < KP2) {
        h1m[rowi * KP2 + t] = 0;
    }
}

extern "C" void kernel_launch(void* const* d_in, const int* in_sizes, int n_in,
                              void* d_out, int out_size, void* d_ws, size_t ws_size,
                              hipStream_t stream)
{
    const void* embeds = d_in[0];
    const void* a_w1 = d_in[1];  const void* a_b1 = d_in[2];
    const void* a_w2 = d_in[3];  const void* a_b2 = d_in[4];
    const void* a_w3 = d_in[5];  const void* a_b3 = d_in[6];
    const void* s_w1 = d_in[7];  const void* s_b1 = d_in[8];
    const void* s_w2 = d_in[9];  const void* s_b2 = d_in[10];
    const void* s_w3 = d_in[11]; const void* s_b3 = d_in[12];
    const int* starts = (const int*)d_in[13];
    const int* lens   = (const int*)d_in[14];

    // workspace layout — ~30 MB
    char* ws = (char*)d_ws;
    int*    dflag = (int*)ws;                  ws += 256;
    ushort* Wbig  = (ushort*)ws;               ws += (size_t)NB*EE*2;        // 1.31 MB
    ushort* a_w2t = (ushort*)ws;               ws += (size_t)HP*KP2*2;       // 60 KB
    ushort* s_w2t = (ushort*)ws;               ws += (size_t)HP*KP2*2;       // 60 KB
    float*  biases = (float*)ws;               ws += (size_t)4*HP*4;         // 2.5 KB
    ushort* h1a  = (ushort*)ws;                ws += (size_t)NT*KP2*2;       // 6.3 MB
    ushort* Pabc = (ushort*)ws;                ws += (size_t)NT*480*2;       // 15.7 MB
    float*  attns = (float*)ws;                ws += (size_t)NT*4;           // 64 KB
    ushort* h1m  = (ushort*)ws;                ws += (size_t)NS*KP2*2;       // 6.1 MB

    detect_kernel<<<1, 1024, 0, stream>>>((const ushort*)embeds, dflag);
    prep_kernel<<<dim3(NB, 4), 256, 0, stream>>>(a_w1, s_w1, a_w2, s_w2,
                                                 a_b1, a_b2, s_b1, s_b2, dflag,
                                                 Wbig, a_w2t, s_w2t, biases);
    // token-level fused layer-1 GEMM (attn h1 + mention projections Pa,Pb,Pc)
    big_gemm_kernel<<<dim3(NT/64, 4), 256, 0, stream>>>(embeds, dflag, Wbig, biases, h1a, Pabc);
    // attn layer-2 + score (fused)
    gemm_relu_dot_kernel<<<NT/64, 256, 0, stream>>>(h1a, a_w2t, biases + HP,
                                                    a_w3, a_b3, dflag, attns, nullptr);
    // spans: output 0 + mention h1 via linearity (XCD-swizzled)
    span_kernel<<<NS, 256, 0, stream>>>(embeds, attns, starts, lens, d_out, dflag,
                                        Pabc, biases + 2*HP, h1m);
    // mention layer-2 + score (fused)
    gemm_relu_dot_kernel<<<NS/64, 256, 0, stream>>>(h1m, s_w2t, biases + 3*HP,
                                                    s_w3, s_b3, dflag, nullptr, d_out);
}

// Round 10
// 130.098 us; speedup vs baseline: 1.5637x; 1.0162x over previous
//
#include <hip/hip_runtime.h>
#include <hip/hip_bf16.h>

// ---------- problem constants ----------
#define BB 8
#define TT 2048
#define EE 1024
#define SS 2000
#define HH 150
#define HP 160     // padded hidden (GEMM N)
#define KP2 192    // padded K for layer-2 GEMMs
#define NB 640     // big-GEMM N: [a_w1 | s_w1a | s_w1b | s_w1c] -> 4 x 160
#define NT (BB*TT)     // 16384 tokens
#define NS (BB*SS)     // 16000 spans
#define SPAN_ELEMS ((long)NS*3072)

#define APLANE 520    // 64*8 + 8 ushorts  (16B pad per k-plane: conflict-free writes)
#define BPLANE 1288   // 160*8 + 8 ushorts

typedef __attribute__((ext_vector_type(8))) short short8;
typedef __attribute__((ext_vector_type(4))) float f32x4;
typedef __attribute__((ext_vector_type(4))) ushort u16x4;

__device__ __forceinline__ float b2f(ushort u) {
    union { uint i; float f; } v; v.i = ((uint)u) << 16; return v.f;
}
__device__ __forceinline__ ushort f2b(float f) {
    uint x = __float_as_uint(f);
    uint r = (x + 0x7fffu + ((x >> 16) & 1u)) >> 16;   // RNE
    return (ushort)r;
}
__device__ __forceinline__ uint f2b2(float lo, float hi) {   // pack 2 bf16 into u32
    return (uint)f2b(lo) | ((uint)f2b(hi) << 16);
}
__device__ __forceinline__ float ldf(const void* p, long i, int f32) {
    return f32 ? ((const float*)p)[i] : b2f(((const ushort*)p)[i]);
}

// ---------- dtype detector (1 = inputs are f32, 0 = bf16) ----------
__global__ void detect_kernel(const ushort* __restrict__ p, int* __restrict__ flag) {
    __shared__ int sh;
    if (threadIdx.x == 0) sh = 0;
    __syncthreads();
    int found = 0;
    for (int i = threadIdx.x; i < 65536; i += 1024) {
        ushort v = p[i];
        if ((v & 0x7f80u) >= 0x4780u) found = 1;   // |bf16| >= 65536 (or inf/nan)
    }
    if (found) sh = 1;
    __syncthreads();
    if (threadIdx.x == 0) flag[0] = sh;
}

// ---------- weight prep ----------
__global__ void prep_kernel(const void* __restrict__ a_w1, const void* __restrict__ s_w1,
                            const void* __restrict__ a_w2, const void* __restrict__ s_w2,
                            const void* __restrict__ a_b1, const void* __restrict__ a_b2,
                            const void* __restrict__ s_b1, const void* __restrict__ s_b2,
                            const int* __restrict__ dflag,
                            ushort* __restrict__ Wbig,
                            ushort* __restrict__ a_w2t, ushort* __restrict__ s_w2t,
                            float* __restrict__ biases)
{
    const int f32 = dflag[0];
    int j = blockIdx.x;
    int which = blockIdx.y;
    int t = threadIdx.x;
    if (which == 0) {          // j in 0..639
        int p = j / 160, jj = j - p * 160;
        for (int k = t; k < EE; k += 256) {
            float v = 0.f;
            if (jj < HH)
                v = (p == 0) ? ldf(a_w1, (long)k * HH + jj, f32)
                             : ldf(s_w1, ((long)(p - 1) * EE + k) * HH + jj, f32);
            Wbig[(long)j * EE + k] = f2b(v);
        }
    } else if (which == 1) {
        if (j < HP)
            for (int k = t; k < KP2; k += 256)
                a_w2t[j * KP2 + k] = (j < HH && k < HH) ? f2b(ldf(a_w2, (long)k * HH + j, f32)) : (ushort)0;
    } else if (which == 2) {
        if (j < HP)
            for (int k = t; k < KP2; k += 256)
                s_w2t[j * KP2 + k] = (j < HH && k < HH) ? f2b(ldf(s_w2, (long)k * HH + j, f32)) : (ushort)0;
    } else {
        if (j == 0 && t < HP) {
            biases[t]          = (t < HH) ? ldf(a_b1, t, f32) : 0.f;
            biases[HP + t]     = (t < HH) ? ldf(a_b2, t, f32) : 0.f;
            biases[2*HP + t]   = (t < HH) ? ldf(s_b1, t, f32) : 0.f;
            biases[3*HP + t]   = (t < HH) ? ldf(s_b2, t, f32) : 0.f;
        }
    }
}

// ---------- big token GEMM: embeds[16384][1024] @ Wbig^T -> 4 col-groups ----------
// T14 reg-staged pipeline, named staging registers (spill-proof).
// 1D grid, XCD-chunk swizzle with cg FASTEST: the 4 col-group siblings of a
// row-tile run temporally adjacent on the SAME XCD -> embeds row-tile fetched
// once into that XCD's L2, 3 sibling reads hit. launch_bounds(256,4): all 1024
// blocks co-resident (4 blocks/CU), VGPR<=128 (est. ~100 used, no spill).
__global__ __launch_bounds__(256, 4) void big_gemm_kernel(
    const void* __restrict__ A, const int* __restrict__ dflag,
    const ushort* __restrict__ Wbig,
    const float* __restrict__ biases,
    ushort* __restrict__ h1a, ushort* __restrict__ Pabc)
{
    __shared__ __align__(16) ushort A2[8*APLANE];   // 8.3 KB
    __shared__ __align__(16) ushort B2[8*BPLANE];   // 20.6 KB

    const int af32 = dflag[0];
    const int t = threadIdx.x;
    // XCD-chunk swizzle (1024 blocks, 8 XCDs, 128 per chunk), cg fastest
    const int bid = blockIdx.x;
    const int local = (bid & 7) * 128 + (bid >> 3);
    const int row0 = (local >> 2) * 64;
    const int cg = local & 3;
    const int lane = t & 63;
    const int w = t >> 6;
    const int wr = w >> 1;
    const int wc = w & 1;
    const int l15 = lane & 15;
    const int lg = lane >> 4;       // 0..3

    f32x4 acc[2][5];
#pragma unroll
    for (int m = 0; m < 2; ++m)
#pragma unroll
        for (int n = 0; n < 5; ++n) acc[m][n] = (f32x4){0.f, 0.f, 0.f, 0.f};

    const int arow = t >> 2;            // 0..63
    const int acol = (t & 3) * 16;      // element offset within K-tile

    // LDS write pointers (loop-invariant)
    ushort* aw0 = &A2[((t & 3) * 2    ) * APLANE + arow * 8];
    ushort* aw1 = &A2[((t & 3) * 2 + 1) * APLANE + arow * 8];
    ushort* bw0 = &B2[(t & 7) * BPLANE + (0*32 + (t >> 3)) * 8];
    ushort* bw1 = &B2[(t & 7) * BPLANE + (1*32 + (t >> 3)) * 8];
    ushort* bw2 = &B2[(t & 7) * BPLANE + (2*32 + (t >> 3)) * 8];
    ushort* bw3 = &B2[(t & 7) * BPLANE + (3*32 + (t >> 3)) * 8];
    ushort* bw4 = &B2[(t & 7) * BPLANE + (4*32 + (t >> 3)) * 8];

    // global source pointers (advance by k0)
    const float*  srcF = (const float*)A  + (long)(row0 + arow) * EE + acol;
    const ushort* srcH = (const ushort*)A + (long)(row0 + arow) * EE + acol;
    const ushort* bs0 = Wbig + (long)(cg*160 + 0*32 + (t >> 3)) * EE + (t & 7) * 8;
    const ushort* bs1 = Wbig + (long)(cg*160 + 1*32 + (t >> 3)) * EE + (t & 7) * 8;
    const ushort* bs2 = Wbig + (long)(cg*160 + 2*32 + (t >> 3)) * EE + (t & 7) * 8;
    const ushort* bs3 = Wbig + (long)(cg*160 + 3*32 + (t >> 3)) * EE + (t & 7) * 8;
    const ushort* bs4 = Wbig + (long)(cg*160 + 4*32 + (t >> 3)) * EE + (t & 7) * 8;

    // named staging registers
    f32x4 raf0, raf1, raf2, raf3;
    uint4 rab0, rab1;
    uint4 rb0, rb1, rb2, rb3, rb4;

#define LOAD_TILE(K0)                                                          \
    do {                                                                       \
        if (af32) {                                                            \
            raf0 = *(const f32x4*)(srcF + (K0));                               \
            raf1 = *(const f32x4*)(srcF + (K0) + 4);                           \
            raf2 = *(const f32x4*)(srcF + (K0) + 8);                           \
            raf3 = *(const f32x4*)(srcF + (K0) + 12);                          \
        } else {                                                               \
            rab0 = *(const uint4*)(srcH + (K0));                               \
            rab1 = *(const uint4*)(srcH + (K0) + 8);                           \
        }                                                                      \
        rb0 = *(const uint4*)(bs0 + (K0));                                     \
        rb1 = *(const uint4*)(bs1 + (K0));                                     \
        rb2 = *(const uint4*)(bs2 + (K0));                                     \
        rb3 = *(const uint4*)(bs3 + (K0));                                     \
        rb4 = *(const uint4*)(bs4 + (K0));                                     \
    } while (0)

#define WRITE_TILE()                                                           \
    do {                                                                       \
        if (af32) {                                                            \
            uint4 w0, w1;                                                      \
            w0.x = f2b2(raf0[0], raf0[1]); w0.y = f2b2(raf0[2], raf0[3]);      \
            w0.z = f2b2(raf1[0], raf1[1]); w0.w = f2b2(raf1[2], raf1[3]);      \
            w1.x = f2b2(raf2[0], raf2[1]); w1.y = f2b2(raf2[2], raf2[3]);      \
            w1.z = f2b2(raf3[0], raf3[1]); w1.w = f2b2(raf3[2], raf3[3]);      \
            *(uint4*)aw0 = w0;                                                 \
            *(uint4*)aw1 = w1;                                                 \
        } else {                                                               \
            *(uint4*)aw0 = rab0;                                               \
            *(uint4*)aw1 = rab1;                                               \
        }                                                                      \
        *(uint4*)bw0 = rb0;                                                    \
        *(uint4*)bw1 = rb1;                                                    \
        *(uint4*)bw2 = rb2;                                                    \
        *(uint4*)bw3 = rb3;                                                    \
        *(uint4*)bw4 = rb4;                                                    \
    } while (0)

    LOAD_TILE(0);
    for (int k0 = 0; k0 < EE; k0 += 64) {
        if (k0) __syncthreads();        // prev tile's MFMA reads done before overwrite
        WRITE_TILE();                   // regs (waitcnt'd) -> LDS
        __syncthreads();                // LDS visible
        if (k0 + 64 < EE) LOAD_TILE(k0 + 64);   // in flight under MFMA phase
#pragma unroll
        for (int ks = 0; ks < 2; ++ks) {
            const int kg = ks * 4 + lg;
            short8 af2[2];
#pragma unroll
            for (int m = 0; m < 2; ++m)
                af2[m] = *(const short8*)&A2[kg * APLANE + (wr*32 + m*16 + l15) * 8];
#pragma unroll
            for (int n = 0; n < 5; ++n) {
                short8 bf = *(const short8*)&B2[kg * BPLANE + (wc*80 + n*16 + l15) * 8];
#pragma unroll
                for (int m = 0; m < 2; ++m)
                    acc[m][n] = __builtin_amdgcn_mfma_f32_16x16x32_bf16(af2[m], bf, acc[m][n], 0, 0, 0);
            }
        }
    }
#undef LOAD_TILE
#undef WRITE_TILE
    if (cg == 0) {
#pragma unroll
        for (int m = 0; m < 2; ++m) {
            int rbase = row0 + wr*32 + m*16 + lg * 4;
#pragma unroll
            for (int n = 0; n < 5; ++n) {
                int col = wc*80 + n*16 + l15;
                float b = biases[col];
#pragma unroll
                for (int r = 0; r < 4; ++r) {
                    float v = acc[m][n][r] + b;
                    v = v > 0.f ? v : 0.f;
                    h1a[(long)(rbase + r) * KP2 + col] = f2b(v);
                }
            }
        }
        int r = t >> 2;
        int c = HP + (t & 3) * 8;
        *(uint4*)(h1a + (long)(row0 + r) * KP2 + c) = (uint4){0,0,0,0};
    } else {
        int cb = (cg - 1) * 160;
#pragma unroll
        for (int m = 0; m < 2; ++m) {
            int rbase = row0 + wr*32 + m*16 + lg * 4;
#pragma unroll
            for (int n = 0; n < 5; ++n) {
                int col = cb + wc*80 + n*16 + l15;
#pragma unroll
                for (int r = 0; r < 4; ++r)
                    Pabc[(long)(rbase + r) * 480 + col] = f2b(acc[m][n][r]);
            }
        }
    }
}

// ---------- fused layer-2 GEMM + score dot ----------
// score[row] = b3 + sum_col relu(A[row]@Wt[col] + bias[col]) * w3[col]
__global__ __launch_bounds__(256) void gemm_relu_dot_kernel(
    const ushort* __restrict__ A,
    const ushort* __restrict__ Wt,
    const float* __restrict__ bias,
    const void* __restrict__ w3, const void* __restrict__ b3,
    const int* __restrict__ dflag,
    float* __restrict__ outf, void* __restrict__ outAll)
{
    __shared__ __align__(16) ushort A2[8*64*8];
    __shared__ __align__(16) ushort B2[8*160*8];
    __shared__ float w3lds[HP];
    __shared__ float red[64][2];

    const int f32 = dflag[0];
    const int t = threadIdx.x;
    const int row0 = blockIdx.x * 64;
    const int lane = t & 63;
    const int w = t >> 6;
    const int wr = w >> 1;
    const int wc = w & 1;
    const int l15 = lane & 15;
    const int kb = (lane >> 4) * 8;

    if (t < HP) w3lds[t] = (t < HH) ? ldf(w3, t, f32) : 0.f;

    f32x4 acc[2][5];
#pragma unroll
    for (int m = 0; m < 2; ++m)
#pragma unroll
        for (int n = 0; n < 5; ++n) acc[m][n] = (f32x4){0.f, 0.f, 0.f, 0.f};

    const int arow = t >> 2;
    const int ag0 = (t & 3) * 2;

    for (int k0 = 0; k0 < KP2; k0 += 64) {
        {
            const ushort* src = A + (long)(row0 + arow) * KP2 + k0 + ag0 * 8;
            *(uint4*)&A2[((ag0    ) * 64 + arow) * 8] = *(const uint4*)(src);
            *(uint4*)&A2[((ag0 + 1) * 64 + arow) * 8] = *(const uint4*)(src + 8);
        }
#pragma unroll
        for (int p = 0; p < 5; ++p) {
            int gg = p * 256 + t;
            int br = gg >> 3;
            int bg = gg & 7;
            uint4 v = *(const uint4*)(Wt + (long)br * KP2 + k0 + bg * 8);
            *(uint4*)&B2[(bg * 160 + br) * 8] = v;
        }
        __syncthreads();
#pragma unroll
        for (int ks = 0; ks < 64; ks += 32) {
            const int kg = (ks + kb) >> 3;
            short8 af[2];
#pragma unroll
            for (int m = 0; m < 2; ++m)
                af[m] = *(const short8*)&A2[(kg * 64 + wr*32 + m*16 + l15) * 8];
#pragma unroll
            for (int n = 0; n < 5; ++n) {
                short8 bf = *(const short8*)&B2[(kg * 160 + wc*80 + n*16 + l15) * 8];
#pragma unroll
                for (int m = 0; m < 2; ++m)
                    acc[m][n] = __builtin_amdgcn_mfma_f32_16x16x32_bf16(af[m], bf, acc[m][n], 0, 0, 0);
            }
        }
        __syncthreads();
    }
    // epilogue: relu + dot(w3) fused, no h2 materialization
    float w3c[5];
    float bc[5];
#pragma unroll
    for (int n = 0; n < 5; ++n) {
        int col = wc*80 + n*16 + l15;
        w3c[n] = w3lds[col];
        bc[n] = bias[col];
    }
    float p[2][4];
#pragma unroll
    for (int m = 0; m < 2; ++m)
#pragma unroll
        for (int r = 0; r < 4; ++r) {
            float s = 0.f;
#pragma unroll
            for (int n = 0; n < 5; ++n) {
                float v = acc[m][n][r] + bc[n];
                v = v > 0.f ? v : 0.f;
                s += v * w3c[n];
            }
            p[m][r] = s;
        }
#pragma unroll
    for (int mask = 1; mask < 16; mask <<= 1)
#pragma unroll
        for (int m = 0; m < 2; ++m)
#pragma unroll
            for (int r = 0; r < 4; ++r)
                p[m][r] += __shfl_xor(p[m][r], mask, 16);
    if (l15 == 0) {
        int g = lane >> 4;
#pragma unroll
        for (int m = 0; m < 2; ++m)
#pragma unroll
            for (int r = 0; r < 4; ++r)
                red[wr*32 + m*16 + g*4 + r][wc] = p[m][r];
    }
    __syncthreads();
    if (t < 64) {
        int row = row0 + t;
        float s = red[t][0] + red[t][1] + ldf(b3, 0, f32);
        if (outf) outf[row] = s;
        else if (f32) ((float*)outAll)[SPAN_ELEMS + row] = s;
        else ((ushort*)outAll)[SPAN_ELEMS + row] = f2b(s);
    }
}

// ---------- span: out0 = [start_e|end_e|span_sum]; h1m = relu(Pa+Pb+Σa·Pc+b) ----------
// 1D grid 16000 with bijective XCD swizzle: XCD k owns batch k's spans in sorted order.
__global__ __launch_bounds__(256) void span_kernel(
    const void* __restrict__ embeds, const float* __restrict__ attns,
    const int* __restrict__ starts, const int* __restrict__ lens,
    void* __restrict__ out, const int* __restrict__ dflag,
    const ushort* __restrict__ Pabc, const float* __restrict__ biases2,
    ushort* __restrict__ h1m)
{
    __shared__ float at[32];
    const int f32 = dflag[0];
    int bid = blockIdx.x;
    int swz = (bid & 7) * (NS / 8) + (bid >> 3);   // bijective (16000 % 8 == 0)
    int b = swz / SS, s = swz - b * SS;
    int t = threadIdx.x;
    int st = starts[b*SS + s];
    int len = lens[b*SS + s];       // inclusive span st..st+len, len+1 <= 30 rows
    int en = st + len;
    if (t < 30) at[t] = attns[b*TT + st + t];
    __syncthreads();
    // ---- phase A: span_embeds -> out (non-temporal stores keep L2 for gather) ----
    int e4 = t * 4;
    long ebase = ((long)(b*TT + st)) * EE + e4;
    long eend  = ((long)(b*TT + en)) * EE + e4;
    long obase = ((long)(b*SS + s)) * 3072 + e4;
    if (!f32) {
        const ushort* E = (const ushort*)embeds;
        ushort* O = (ushort*)out;
        u16x4 se = *(const u16x4*)(E + ebase);
        u16x4 ed = *(const u16x4*)(E + eend);
        float ax = 0.f, ay = 0.f, az = 0.f, aw = 0.f;
        for (int i = 0; i <= len; ++i) {
            float a = at[i];
            u16x4 v = *(const u16x4*)(E + ebase + (long)i * EE);
            ax += b2f(v.x) * a; ay += b2f(v.y) * a;
            az += b2f(v.z) * a; aw += b2f(v.w) * a;
        }
        u16x4 sm; sm.x = f2b(ax); sm.y = f2b(ay); sm.z = f2b(az); sm.w = f2b(aw);
        __builtin_nontemporal_store(se, (u16x4*)(O + obase));
        __builtin_nontemporal_store(ed, (u16x4*)(O + obase + 1024));
        __builtin_nontemporal_store(sm, (u16x4*)(O + obase + 2048));
    } else {
        const float* E = (const float*)embeds;
        float* O = (float*)out;
        f32x4 se = *(const f32x4*)(E + ebase);
        f32x4 ed = *(const f32x4*)(E + eend);
        float ax = 0.f, ay = 0.f, az = 0.f, aw = 0.f;
        for (int i = 0; i <= len; ++i) {
            float a = at[i];
            f32x4 v = *(const f32x4*)(E + ebase + (long)i * EE);
            ax += v.x * a; ay += v.y * a; az += v.z * a; aw += v.w * a;
        }
        f32x4 sm = {ax, ay, az, aw};
        __builtin_nontemporal_store(se, (f32x4*)(O + obase));
        __builtin_nontemporal_store(ed, (f32x4*)(O + obase + 1024));
        __builtin_nontemporal_store(sm, (f32x4*)(O + obase + 2048));
    }
    // ---- phase B: mention-layer-1 row via linearity ----
    long rowi = (long)(b*SS + s);
    if (t < HP) {
        float acc = biases2[t]
                  + b2f(Pabc[((long)(b*TT + st)) * 480 + t])
                  + b2f(Pabc[((long)(b*TT + en)) * 480 + 160 + t]);
        const ushort* pc = Pabc + ((long)(b*TT + st)) * 480 + 320 + t;
        for (int i = 0; i <= len; ++i) acc += at[i] * b2f(pc[(long)i * 480]);
        acc = acc > 0.f ? acc : 0.f;
        h1m[rowi * KP2 + t] = f2b(acc);
    } else if (t < KP2) {
        h1m[rowi * KP2 + t] = 0;
    }
}

extern "C" void kernel_launch(void* const* d_in, const int* in_sizes, int n_in,
                              void* d_out, int out_size, void* d_ws, size_t ws_size,
                              hipStream_t stream)
{
    const void* embeds = d_in[0];
    const void* a_w1 = d_in[1];  const void* a_b1 = d_in[2];
    const void* a_w2 = d_in[3];  const void* a_b2 = d_in[4];
    const void* a_w3 = d_in[5];  const void* a_b3 = d_in[6];
    const void* s_w1 = d_in[7];  const void* s_b1 = d_in[8];
    const void* s_w2 = d_in[9];  const void* s_b2 = d_in[10];
    const void* s_w3 = d_in[11]; const void* s_b3 = d_in[12];
    const int* starts = (const int*)d_in[13];
    const int* lens   = (const int*)d_in[14];

    // workspace layout — ~30 MB
    char* ws = (char*)d_ws;
    int*    dflag = (int*)ws;                  ws += 256;
    ushort* Wbig  = (ushort*)ws;               ws += (size_t)NB*EE*2;        // 1.31 MB
    ushort* a_w2t = (ushort*)ws;               ws += (size_t)HP*KP2*2;       // 60 KB
    ushort* s_w2t = (ushort*)ws;               ws += (size_t)HP*KP2*2;       // 60 KB
    float*  biases = (float*)ws;               ws += (size_t)4*HP*4;         // 2.5 KB
    ushort* h1a  = (ushort*)ws;                ws += (size_t)NT*KP2*2;       // 6.3 MB
    ushort* Pabc = (ushort*)ws;                ws += (size_t)NT*480*2;       // 15.7 MB
    float*  attns = (float*)ws;                ws += (size_t)NT*4;           // 64 KB
    ushort* h1m  = (ushort*)ws;                ws += (size_t)NS*KP2*2;       // 6.1 MB

    detect_kernel<<<1, 1024, 0, stream>>>((const ushort*)embeds, dflag);
    prep_kernel<<<dim3(NB, 4), 256, 0, stream>>>(a_w1, s_w1, a_w2, s_w2,
                                                 a_b1, a_b2, s_b1, s_b2, dflag,
                                                 Wbig, a_w2t, s_w2t, biases);
    // token-level fused layer-1 GEMM (attn h1 + mention projections Pa,Pb,Pc)
    big_gemm_kernel<<<NT/64*4, 256, 0, stream>>>(embeds, dflag, Wbig, biases, h1a, Pabc);
    // attn layer-2 + score (fused)
    gemm_relu_dot_kernel<<<NT/64, 256, 0, stream>>>(h1a, a_w2t, biases + HP,
                                                    a_w3, a_b3, dflag, attns, nullptr);
    // spans: output 0 + mention h1 via linearity (XCD-swizzled)
    span_kernel<<<NS, 256, 0, stream>>>(embeds, attns, starts, lens, d_out, dflag,
                                        Pabc, biases + 2*HP, h1m);
    // mention layer-2 + score (fused)
    gemm_relu_dot_kernel<<<NS/64, 256, 0, stream>>>(h1m, s_w2t, biases + 3*HP,
                                                    s_w3, s_b3, dflag, nullptr, d_out);
}

// Round 12
// 129.819 us; speedup vs baseline: 1.5670x; 1.0021x over previous
//
#include <hip/hip_runtime.h>
#include <hip/hip_bf16.h>

// ---------- problem constants ----------
#define BB 8
#define TT 2048
#define EE 1024
#define SS 2000
#define HH 150
#define HP 160     // padded hidden (GEMM N)
#define KP2 192    // padded K for layer-2 GEMMs
#define NB 640     // big-GEMM N: [a_w1 | s_w1a | s_w1b | s_w1c] -> 4 x 160
#define NT (BB*TT)     // 16384 tokens
#define NS (BB*SS)     // 16000 spans
#define SPAN_ELEMS ((long)NS*3072)

#define APLANE 520    // 64*8 + 8 ushorts  (16B pad per k-plane: conflict-free writes)
#define BPLANE 1288   // 160*8 + 8 ushorts

typedef __attribute__((ext_vector_type(8))) short short8;
typedef __attribute__((ext_vector_type(4))) float f32x4;
typedef __attribute__((ext_vector_type(4))) ushort u16x4;

__device__ __forceinline__ float b2f(ushort u) {
    union { uint i; float f; } v; v.i = ((uint)u) << 16; return v.f;
}
// HW bf16 conversion (RNE): __float2bfloat16 lowers to the native cvt on gfx950.
__device__ __forceinline__ ushort f2b(float f) {
    union { __hip_bfloat16 b; ushort u; } v; v.b = __float2bfloat16(f); return v.u;
}
__device__ __forceinline__ uint f2b2(float lo, float hi) {   // pack 2 bf16 into u32
    return (uint)f2b(lo) | ((uint)f2b(hi) << 16);
}
__device__ __forceinline__ float ldf(const void* p, long i, int f32) {
    return f32 ? ((const float*)p)[i] : b2f(((const ushort*)p)[i]);
}

// ---------- dtype detector (1 = inputs are f32, 0 = bf16) ----------
__global__ void detect_kernel(const ushort* __restrict__ p, int* __restrict__ flag) {
    __shared__ int sh;
    if (threadIdx.x == 0) sh = 0;
    __syncthreads();
    int found = 0;
    for (int i = threadIdx.x; i < 65536; i += 1024) {
        ushort v = p[i];
        if ((v & 0x7f80u) >= 0x4780u) found = 1;   // |bf16| >= 65536 (or inf/nan)
    }
    if (found) sh = 1;
    __syncthreads();
    if (threadIdx.x == 0) flag[0] = sh;
}

// ---------- weight prep ----------
__global__ void prep_kernel(const void* __restrict__ a_w1, const void* __restrict__ s_w1,
                            const void* __restrict__ a_w2, const void* __restrict__ s_w2,
                            const void* __restrict__ a_b1, const void* __restrict__ a_b2,
                            const void* __restrict__ s_b1, const void* __restrict__ s_b2,
                            const int* __restrict__ dflag,
                            ushort* __restrict__ Wbig,
                            ushort* __restrict__ a_w2t, ushort* __restrict__ s_w2t,
                            float* __restrict__ biases)
{
    const int f32 = dflag[0];
    int j = blockIdx.x;
    int which = blockIdx.y;
    int t = threadIdx.x;
    if (which == 0) {          // j in 0..639
        int p = j / 160, jj = j - p * 160;
        for (int k = t; k < EE; k += 256) {
            float v = 0.f;
            if (jj < HH)
                v = (p == 0) ? ldf(a_w1, (long)k * HH + jj, f32)
                             : ldf(s_w1, ((long)(p - 1) * EE + k) * HH + jj, f32);
            Wbig[(long)j * EE + k] = f2b(v);
        }
    } else if (which == 1) {
        if (j < HP)
            for (int k = t; k < KP2; k += 256)
                a_w2t[j * KP2 + k] = (j < HH && k < HH) ? f2b(ldf(a_w2, (long)k * HH + j, f32)) : (ushort)0;
    } else if (which == 2) {
        if (j < HP)
            for (int k = t; k < KP2; k += 256)
                s_w2t[j * KP2 + k] = (j < HH && k < HH) ? f2b(ldf(s_w2, (long)k * HH + j, f32)) : (ushort)0;
    } else {
        if (j == 0 && t < HP) {
            biases[t]          = (t < HH) ? ldf(a_b1, t, f32) : 0.f;
            biases[HP + t]     = (t < HH) ? ldf(a_b2, t, f32) : 0.f;
            biases[2*HP + t]   = (t < HH) ? ldf(s_b1, t, f32) : 0.f;
            biases[3*HP + t]   = (t < HH) ? ldf(s_b2, t, f32) : 0.f;
        }
    }
}

// ---------- big token GEMM: embeds[16384][1024] @ Wbig^T -> 4 col-groups ----------
// T14 reg-staged pipeline, named staging registers (spill-proof), HW bf16 cvt.
// 1D grid, XCD-chunk swizzle with cg fastest; launch_bounds(256,4).
__global__ __launch_bounds__(256, 4) void big_gemm_kernel(
    const void* __restrict__ A, const int* __restrict__ dflag,
    const ushort* __restrict__ Wbig,
    const float* __restrict__ biases,
    ushort* __restrict__ h1a, ushort* __restrict__ Pabc)
{
    __shared__ __align__(16) ushort A2[8*APLANE];   // 8.3 KB
    __shared__ __align__(16) ushort B2[8*BPLANE];   // 20.6 KB

    const int af32 = dflag[0];
    const int t = threadIdx.x;
    // XCD-chunk swizzle (1024 blocks, 8 XCDs, 128 per chunk), cg fastest
    const int bid = blockIdx.x;
    const int local = (bid & 7) * 128 + (bid >> 3);
    const int row0 = (local >> 2) * 64;
    const int cg = local & 3;
    const int lane = t & 63;
    const int w = t >> 6;
    const int wr = w >> 1;
    const int wc = w & 1;
    const int l15 = lane & 15;
    const int lg = lane >> 4;       // 0..3

    f32x4 acc[2][5];
#pragma unroll
    for (int m = 0; m < 2; ++m)
#pragma unroll
        for (int n = 0; n < 5; ++n) acc[m][n] = (f32x4){0.f, 0.f, 0.f, 0.f};

    const int arow = t >> 2;            // 0..63
    const int acol = (t & 3) * 16;      // element offset within K-tile

    // LDS write pointers (loop-invariant)
    ushort* aw0 = &A2[((t & 3) * 2    ) * APLANE + arow * 8];
    ushort* aw1 = &A2[((t & 3) * 2 + 1) * APLANE + arow * 8];
    ushort* bw0 = &B2[(t & 7) * BPLANE + (0*32 + (t >> 3)) * 8];
    ushort* bw1 = &B2[(t & 7) * BPLANE + (1*32 + (t >> 3)) * 8];
    ushort* bw2 = &B2[(t & 7) * BPLANE + (2*32 + (t >> 3)) * 8];
    ushort* bw3 = &B2[(t & 7) * BPLANE + (3*32 + (t >> 3)) * 8];
    ushort* bw4 = &B2[(t & 7) * BPLANE + (4*32 + (t >> 3)) * 8];

    // global source pointers (advance by k0)
    const float*  srcF = (const float*)A  + (long)(row0 + arow) * EE + acol;
    const ushort* srcH = (const ushort*)A + (long)(row0 + arow) * EE + acol;
    const ushort* bs0 = Wbig + (long)(cg*160 + 0*32 + (t >> 3)) * EE + (t & 7) * 8;
    const ushort* bs1 = Wbig + (long)(cg*160 + 1*32 + (t >> 3)) * EE + (t & 7) * 8;
    const ushort* bs2 = Wbig + (long)(cg*160 + 2*32 + (t >> 3)) * EE + (t & 7) * 8;
    const ushort* bs3 = Wbig + (long)(cg*160 + 3*32 + (t >> 3)) * EE + (t & 7) * 8;
    const ushort* bs4 = Wbig + (long)(cg*160 + 4*32 + (t >> 3)) * EE + (t & 7) * 8;

    // named staging registers
    f32x4 raf0, raf1, raf2, raf3;
    uint4 rab0, rab1;
    uint4 rb0, rb1, rb2, rb3, rb4;

#define LOAD_TILE(K0)                                                          \
    do {                                                                       \
        if (af32) {                                                            \
            raf0 = *(const f32x4*)(srcF + (K0));                               \
            raf1 = *(const f32x4*)(srcF + (K0) + 4);                           \
            raf2 = *(const f32x4*)(srcF + (K0) + 8);                           \
            raf3 = *(const f32x4*)(srcF + (K0) + 12);                          \
        } else {                                                               \
            rab0 = *(const uint4*)(srcH + (K0));                               \
            rab1 = *(const uint4*)(srcH + (K0) + 8);                           \
        }                                                                      \
        rb0 = *(const uint4*)(bs0 + (K0));                                     \
        rb1 = *(const uint4*)(bs1 + (K0));                                     \
        rb2 = *(const uint4*)(bs2 + (K0));                                     \
        rb3 = *(const uint4*)(bs3 + (K0));                                     \
        rb4 = *(const uint4*)(bs4 + (K0));                                     \
    } while (0)

#define WRITE_TILE()                                                           \
    do {                                                                       \
        if (af32) {                                                            \
            uint4 w0, w1;                                                      \
            w0.x = f2b2(raf0[0], raf0[1]); w0.y = f2b2(raf0[2], raf0[3]);      \
            w0.z = f2b2(raf1[0], raf1[1]); w0.w = f2b2(raf1[2], raf1[3]);      \
            w1.x = f2b2(raf2[0], raf2[1]); w1.y = f2b2(raf2[2], raf2[3]);      \
            w1.z = f2b2(raf3[0], raf3[1]); w1.w = f2b2(raf3[2], raf3[3]);      \
            *(uint4*)aw0 = w0;                                                 \
            *(uint4*)aw1 = w1;                                                 \
        } else {                                                               \
            *(uint4*)aw0 = rab0;                                               \
            *(uint4*)aw1 = rab1;                                               \
        }                                                                      \
        *(uint4*)bw0 = rb0;                                                    \
        *(uint4*)bw1 = rb1;                                                    \
        *(uint4*)bw2 = rb2;                                                    \
        *(uint4*)bw3 = rb3;                                                    \
        *(uint4*)bw4 = rb4;                                                    \
    } while (0)

    LOAD_TILE(0);
    for (int k0 = 0; k0 < EE; k0 += 64) {
        if (k0) __syncthreads();        // prev tile's MFMA reads done before overwrite
        WRITE_TILE();                   // regs (waitcnt'd) -> LDS
        __syncthreads();                // LDS visible
        if (k0 + 64 < EE) LOAD_TILE(k0 + 64);   // in flight under MFMA phase
#pragma unroll
        for (int ks = 0; ks < 2; ++ks) {
            const int kg = ks * 4 + lg;
            short8 af2[2];
#pragma unroll
            for (int m = 0; m < 2; ++m)
                af2[m] = *(const short8*)&A2[kg * APLANE + (wr*32 + m*16 + l15) * 8];
#pragma unroll
            for (int n = 0; n < 5; ++n) {
                short8 bf = *(const short8*)&B2[kg * BPLANE + (wc*80 + n*16 + l15) * 8];
#pragma unroll
                for (int m = 0; m < 2; ++m)
                    acc[m][n] = __builtin_amdgcn_mfma_f32_16x16x32_bf16(af2[m], bf, acc[m][n], 0, 0, 0);
            }
        }
    }
#undef LOAD_TILE
#undef WRITE_TILE
    if (cg == 0) {
#pragma unroll
        for (int m = 0; m < 2; ++m) {
            int rbase = row0 + wr*32 + m*16 + lg * 4;
#pragma unroll
            for (int n = 0; n < 5; ++n) {
                int col = wc*80 + n*16 + l15;
                float b = biases[col];
#pragma unroll
                for (int r = 0; r < 4; ++r) {
                    float v = acc[m][n][r] + b;
                    v = v > 0.f ? v : 0.f;
                    h1a[(long)(rbase + r) * KP2 + col] = f2b(v);
                }
            }
        }
        int r = t >> 2;
        int c = HP + (t & 3) * 8;
        *(uint4*)(h1a + (long)(row0 + r) * KP2 + c) = (uint4){0,0,0,0};
    } else {
        int cb = (cg - 1) * 160;
#pragma unroll
        for (int m = 0; m < 2; ++m) {
            int rbase = row0 + wr*32 + m*16 + lg * 4;
#pragma unroll
            for (int n = 0; n < 5; ++n) {
                int col = cb + wc*80 + n*16 + l15;
#pragma unroll
                for (int r = 0; r < 4; ++r)
                    Pabc[(long)(rbase + r) * 480 + col] = f2b(acc[m][n][r]);
            }
        }
    }
}

// ---------- fused layer-2 GEMM + score dot ----------
// score[row] = b3 + sum_col relu(A[row]@Wt[col] + bias[col]) * w3[col]
__global__ __launch_bounds__(256) void gemm_relu_dot_kernel(
    const ushort* __restrict__ A,
    const ushort* __restrict__ Wt,
    const float* __restrict__ bias,
    const void* __restrict__ w3, const void* __restrict__ b3,
    const int* __restrict__ dflag,
    float* __restrict__ outf, void* __restrict__ outAll)
{
    __shared__ __align__(16) ushort A2[8*64*8];
    __shared__ __align__(16) ushort B2[8*160*8];
    __shared__ float w3lds[HP];
    __shared__ float red[64][2];

    const int f32 = dflag[0];
    const int t = threadIdx.x;
    const int row0 = blockIdx.x * 64;
    const int lane = t & 63;
    const int w = t >> 6;
    const int wr = w >> 1;
    const int wc = w & 1;
    const int l15 = lane & 15;
    const int kb = (lane >> 4) * 8;

    if (t < HP) w3lds[t] = (t < HH) ? ldf(w3, t, f32) : 0.f;

    f32x4 acc[2][5];
#pragma unroll
    for (int m = 0; m < 2; ++m)
#pragma unroll
        for (int n = 0; n < 5; ++n) acc[m][n] = (f32x4){0.f, 0.f, 0.f, 0.f};

    const int arow = t >> 2;
    const int ag0 = (t & 3) * 2;

    for (int k0 = 0; k0 < KP2; k0 += 64) {
        {
            const ushort* src = A + (long)(row0 + arow) * KP2 + k0 + ag0 * 8;
            *(uint4*)&A2[((ag0    ) * 64 + arow) * 8] = *(const uint4*)(src);
            *(uint4*)&A2[((ag0 + 1) * 64 + arow) * 8] = *(const uint4*)(src + 8);
        }
#pragma unroll
        for (int p = 0; p < 5; ++p) {
            int gg = p * 256 + t;
            int br = gg >> 3;
            int bg = gg & 7;
            uint4 v = *(const uint4*)(Wt + (long)br * KP2 + k0 + bg * 8);
            *(uint4*)&B2[(bg * 160 + br) * 8] = v;
        }
        __syncthreads();
#pragma unroll
        for (int ks = 0; ks < 64; ks += 32) {
            const int kg = (ks + kb) >> 3;
            short8 af[2];
#pragma unroll
            for (int m = 0; m < 2; ++m)
                af[m] = *(const short8*)&A2[(kg * 64 + wr*32 + m*16 + l15) * 8];
#pragma unroll
            for (int n = 0; n < 5; ++n) {
                short8 bf = *(const short8*)&B2[(kg * 160 + wc*80 + n*16 + l15) * 8];
#pragma unroll
                for (int m = 0; m < 2; ++m)
                    acc[m][n] = __builtin_amdgcn_mfma_f32_16x16x32_bf16(af[m], bf, acc[m][n], 0, 0, 0);
            }
        }
        __syncthreads();
    }
    // epilogue: relu + dot(w3) fused, no h2 materialization
    float w3c[5];
    float bc[5];
#pragma unroll
    for (int n = 0; n < 5; ++n) {
        int col = wc*80 + n*16 + l15;
        w3c[n] = w3lds[col];
        bc[n] = bias[col];
    }
    float p[2][4];
#pragma unroll
    for (int m = 0; m < 2; ++m)
#pragma unroll
        for (int r = 0; r < 4; ++r) {
            float s = 0.f;
#pragma unroll
            for (int n = 0; n < 5; ++n) {
                float v = acc[m][n][r] + bc[n];
                v = v > 0.f ? v : 0.f;
                s += v * w3c[n];
            }
            p[m][r] = s;
        }
#pragma unroll
    for (int mask = 1; mask < 16; mask <<= 1)
#pragma unroll
        for (int m = 0; m < 2; ++m)
#pragma unroll
            for (int r = 0; r < 4; ++r)
                p[m][r] += __shfl_xor(p[m][r], mask, 16);
    if (l15 == 0) {
        int g = lane >> 4;
#pragma unroll
        for (int m = 0; m < 2; ++m)
#pragma unroll
            for (int r = 0; r < 4; ++r)
                red[wr*32 + m*16 + g*4 + r][wc] = p[m][r];
    }
    __syncthreads();
    if (t < 64) {
        int row = row0 + t;
        float s = red[t][0] + red[t][1] + ldf(b3, 0, f32);
        if (outf) outf[row] = s;
        else if (f32) ((float*)outAll)[SPAN_ELEMS + row] = s;
        else ((ushort*)outAll)[SPAN_ELEMS + row] = f2b(s);
    }
}

// ---------- span: out0 = [start_e|end_e|span_sum]; h1m = relu(Pa+Pb+Σa·Pc+b) ----------
// 1D grid 16000 with bijective XCD swizzle: XCD k owns batch k's spans in sorted order.
__global__ __launch_bounds__(256) void span_kernel(
    const void* __restrict__ embeds, const float* __restrict__ attns,
    const int* __restrict__ starts, const int* __restrict__ lens,
    void* __restrict__ out, const int* __restrict__ dflag,
    const ushort* __restrict__ Pabc, const float* __restrict__ biases2,
    ushort* __restrict__ h1m)
{
    __shared__ float at[32];
    const int f32 = dflag[0];
    int bid = blockIdx.x;
    int swz = (bid & 7) * (NS / 8) + (bid >> 3);   // bijective (16000 % 8 == 0)
    int b = swz / SS, s = swz - b * SS;
    int t = threadIdx.x;
    int st = starts[b*SS + s];
    int len = lens[b*SS + s];       // inclusive span st..st+len, len+1 <= 30 rows
    int en = st + len;
    if (t < 30) at[t] = attns[b*TT + st + t];
    __syncthreads();
    // ---- phase A: span_embeds -> out (non-temporal stores keep L2 for gather) ----
    int e4 = t * 4;
    long ebase = ((long)(b*TT + st)) * EE + e4;
    long eend  = ((long)(b*TT + en)) * EE + e4;
    long obase = ((long)(b*SS + s)) * 3072 + e4;
    if (!f32) {
        const ushort* E = (const ushort*)embeds;
        ushort* O = (ushort*)out;
        u16x4 se = *(const u16x4*)(E + ebase);
        u16x4 ed = *(const u16x4*)(E + eend);
        float ax = 0.f, ay = 0.f, az = 0.f, aw = 0.f;
        for (int i = 0; i <= len; ++i) {
            float a = at[i];
            u16x4 v = *(const u16x4*)(E + ebase + (long)i * EE);
            ax += b2f(v.x) * a; ay += b2f(v.y) * a;
            az += b2f(v.z) * a; aw += b2f(v.w) * a;
        }
        u16x4 sm; sm.x = f2b(ax); sm.y = f2b(ay); sm.z = f2b(az); sm.w = f2b(aw);
        __builtin_nontemporal_store(se, (u16x4*)(O + obase));
        __builtin_nontemporal_store(ed, (u16x4*)(O + obase + 1024));
        __builtin_nontemporal_store(sm, (u16x4*)(O + obase + 2048));
    } else {
        const float* E = (const float*)embeds;
        float* O = (float*)out;
        f32x4 se = *(const f32x4*)(E + ebase);
        f32x4 ed = *(const f32x4*)(E + eend);
        float ax = 0.f, ay = 0.f, az = 0.f, aw = 0.f;
        for (int i = 0; i <= len; ++i) {
            float a = at[i];
            f32x4 v = *(const f32x4*)(E + ebase + (long)i * EE);
            ax += v.x * a; ay += v.y * a; az += v.z * a; aw += v.w * a;
        }
        f32x4 sm = {ax, ay, az, aw};
        __builtin_nontemporal_store(se, (f32x4*)(O + obase));
        __builtin_nontemporal_store(ed, (f32x4*)(O + obase + 1024));
        __builtin_nontemporal_store(sm, (f32x4*)(O + obase + 2048));
    }
    // ---- phase B: mention-layer-1 row via linearity ----
    long rowi = (long)(b*SS + s);
    if (t < HP) {
        float acc = biases2[t]
                  + b2f(Pabc[((long)(b*TT + st)) * 480 + t])
                  + b2f(Pabc[((long)(b*TT + en)) * 480 + 160 + t]);
        const ushort* pc = Pabc + ((long)(b*TT + st)) * 480 + 320 + t;
        for (int i = 0; i <= len; ++i) acc += at[i] * b2f(pc[(long)i * 480]);
        acc = acc > 0.f ? acc : 0.f;
        h1m[rowi * KP2 + t] = f2b(acc);
    } else if (t < KP2) {
        h1m[rowi * KP2 + t] = 0;
    }
}

extern "C" void kernel_launch(void* const* d_in, const int* in_sizes, int n_in,
                              void* d_out, int out_size, void* d_ws, size_t ws_size,
                              hipStream_t stream)
{
    const void* embeds = d_in[0];
    const void* a_w1 = d_in[1];  const void* a_b1 = d_in[2];
    const void* a_w2 = d_in[3];  const void* a_b2 = d_in[4];
    const void* a_w3 = d_in[5];  const void* a_b3 = d_in[6];
    const void* s_w1 = d_in[7];  const void* s_b1 = d_in[8];
    const void* s_w2 = d_in[9];  const void* s_b2 = d_in[10];
    const void* s_w3 = d_in[11]; const void* s_b3 = d_in[12];
    const int* starts = (const int*)d_in[13];
    const int* lens   = (const int*)d_in[14];

    // workspace layout — ~30 MB
    char* ws = (char*)d_ws;
    int*    dflag = (int*)ws;                  ws += 256;
    ushort* Wbig  = (ushort*)ws;               ws += (size_t)NB*EE*2;        // 1.31 MB
    ushort* a_w2t = (ushort*)ws;               ws += (size_t)HP*KP2*2;       // 60 KB
    ushort* s_w2t = (ushort*)ws;               ws += (size_t)HP*KP2*2;       // 60 KB
    float*  biases = (float*)ws;               ws += (size_t)4*HP*4;         // 2.5 KB
    ushort* h1a  = (ushort*)ws;                ws += (size_t)NT*KP2*2;       // 6.3 MB
    ushort* Pabc = (ushort*)ws;                ws += (size_t)NT*480*2;       // 15.7 MB
    float*  attns = (float*)ws;                ws += (size_t)NT*4;           // 64 KB
    ushort* h1m  = (ushort*)ws;                ws += (size_t)NS*KP2*2;       // 6.1 MB

    detect_kernel<<<1, 1024, 0, stream>>>((const ushort*)embeds, dflag);
    prep_kernel<<<dim3(NB, 4), 256, 0, stream>>>(a_w1, s_w1, a_w2, s_w2,
                                                 a_b1, a_b2, s_b1, s_b2, dflag,
                                                 Wbig, a_w2t, s_w2t, biases);
    // token-level fused layer-1 GEMM (attn h1 + mention projections Pa,Pb,Pc)
    big_gemm_kernel<<<NT/64*4, 256, 0, stream>>>(embeds, dflag, Wbig, biases, h1a, Pabc);
    // attn layer-2 + score (fused)
    gemm_relu_dot_kernel<<<NT/64, 256, 0, stream>>>(h1a, a_w2t, biases + HP,
                                                    a_w3, a_b3, dflag, attns, nullptr);
    // spans: output 0 + mention h1 via linearity (XCD-swizzled)
    span_kernel<<<NS, 256, 0, stream>>>(embeds, attns, starts, lens, d_out, dflag,
                                        Pabc, biases + 2*HP, h1m);
    // mention layer-2 + score (fused)
    gemm_relu_dot_kernel<<<NS/64, 256, 0, stream>>>(h1m, s_w2t, biases + 3*HP,
                                                    s_w3, s_b3, dflag, nullptr, d_out);
}